// Round 8
// baseline (6864980.469 us; speedup 1.0000x reference)
//
#include <hip/hip_runtime.h>
#include <hip/hip_bf16.h>

typedef __attribute__((ext_vector_type(8))) short short8;
typedef __attribute__((ext_vector_type(4))) float f32x4;
typedef unsigned long long u64;

#define MFMA16(A, B, C) __builtin_amdgcn_mfma_f32_16x16x32_bf16((A), (B), (C), 0, 0, 0)

static constexpr int kS = 512;   // seq
static constexpr int kI = 256;   // in_dim
static constexpr int kH = 2048;  // hidden
static constexpr int kC = 1024;  // classes
static constexpr int kBt = 256;  // batch

// WG tile: 32 batch rows x 64 hidden cols. Rowgroup (32 rows) == physical XCD
// when placement is clean (forced by 1 WG/CU co-residency: 139KB LDS, 256 WGs,
// 256 CUs, 32 CUs/XCD). h exchange then lives in the XCD's L2 (sc0 loads +
// plain write-through stores + sc0 flags). Detector: any per-XCD ticket >= 32
// => broken => bijective fallback mapping + validated LLC protocol (== R7).
// LDS:
//   [0,      131072): h-stage [32 rows][2048 k] bf16, stride 4096 B, XOR swizzle
//                     (epilogue reuse: Wph^T [32 cls-cols][2048 k])
//   [131072, 139264): K-half zone [32 rows][16 quads f32x4], XOR swizzle
static constexpr int ZONE_OFF = 131072;

__device__ __forceinline__ int swz(int row, int kbyte) {
  return row * 4096 + (kbyte ^ ((row & 7) << 4));
}
__device__ __forceinline__ f32x4* zslot(char* smem, int row, int quad) {
  return (f32x4*)(smem + ZONE_OFF + row * 256 + (((quad ^ row) & 15) << 4));
}
__device__ __forceinline__ f32x4* zslot2(char* smem, int row, int quad) {
  return (f32x4*)(smem + ZONE_OFF + row * 128 + (((quad ^ row) & 7) << 4));
}

__device__ __forceinline__ unsigned short f2bf(float f) {  // RNE fp32->bf16
  unsigned u = __float_as_uint(f);
  u += 0x7fffu + ((u >> 16) & 1u);
  return (unsigned short)(u >> 16);
}

__device__ __forceinline__ float fast_tanh(float v) {
  float a = __builtin_fabsf(v);
  float e = __expf(-2.0f * a);
  float r = (1.0f - e) / (1.0f + e);
  return __builtin_copysignf(r, v);
}

// ---- validated LLC-coherent intrinsic path (rounds 2-5, 7) ----
__device__ __forceinline__ u64 ld_h8(const u64* p) {
  return __hip_atomic_load(p, __ATOMIC_RELAXED, __HIP_MEMORY_SCOPE_AGENT);
}
__device__ __forceinline__ void st_h8(u64* p, u64 v) {
  __hip_atomic_store(p, v, __ATOMIC_RELAXED, __HIP_MEMORY_SCOPE_AGENT);
}
__device__ __forceinline__ unsigned ld_flag(const unsigned* p) {
  return __hip_atomic_load(p, __ATOMIC_RELAXED, __HIP_MEMORY_SCOPE_AGENT);
}
__device__ __forceinline__ void st_flag(unsigned* p, unsigned v) {
  __hip_atomic_store(p, v, __ATOMIC_RELAXED, __HIP_MEMORY_SCOPE_AGENT);
}
// ---- L2-scope (sc0) path: valid only when rowgroup == XCD (verified) ----
__device__ __forceinline__ unsigned ld_flag_l2(const unsigned* p) {
  unsigned r;
  asm volatile("global_load_dword %0, %1, off sc0\n\ts_waitcnt vmcnt(0)"
               : "=v"(r) : "v"(p) : "memory");
  return r;
}
__device__ __forceinline__ void st_flag_l2(unsigned* p, unsigned v) {
  asm volatile("global_store_dword %0, %1, off sc0" :: "v"(p), "v"(v) : "memory");
}
__device__ __forceinline__ u64 ld8_l2(const u64* p) {
  u64 r;
  asm volatile("global_load_dwordx2 %0, %1, off sc0\n\ts_waitcnt vmcnt(0)"
               : "=v"(r) : "v"(p) : "memory");
  return r;
}

// one staging batch: 8 x 16B loads from HPP(+0..1792), LDS at KB(+0..1792)
#define STAGE_BATCH(HPP, KB, CPOL) do {                                      \
  f32x4 a0, a1, a2, a3, a4, a5, a6, a7;                                      \
  asm volatile(                                                              \
      "global_load_dwordx4 %0, %8, off" CPOL "\n\t"                          \
      "global_load_dwordx4 %1, %8, off offset:256" CPOL "\n\t"               \
      "global_load_dwordx4 %2, %8, off offset:512" CPOL "\n\t"               \
      "global_load_dwordx4 %3, %8, off offset:768" CPOL "\n\t"               \
      "global_load_dwordx4 %4, %8, off offset:1024" CPOL "\n\t"              \
      "global_load_dwordx4 %5, %8, off offset:1280" CPOL "\n\t"              \
      "global_load_dwordx4 %6, %8, off offset:1536" CPOL "\n\t"              \
      "global_load_dwordx4 %7, %8, off offset:1792" CPOL                     \
      : "=&v"(a0), "=&v"(a1), "=&v"(a2), "=&v"(a3),                          \
        "=&v"(a4), "=&v"(a5), "=&v"(a6), "=&v"(a7)                           \
      : "v"(HPP) : "memory");                                                \
  asm volatile("s_waitcnt vmcnt(0)" ::: "memory");                           \
  __builtin_amdgcn_sched_barrier(0);                                         \
  *(f32x4*)(smem + swz(srow, (KB)))        = a0;                             \
  *(f32x4*)(smem + swz(srow, (KB) + 256))  = a1;                             \
  *(f32x4*)(smem + swz(srow, (KB) + 512))  = a2;                             \
  *(f32x4*)(smem + swz(srow, (KB) + 768))  = a3;                             \
  *(f32x4*)(smem + swz(srow, (KB) + 1024)) = a4;                             \
  *(f32x4*)(smem + swz(srow, (KB) + 1280)) = a5;                             \
  *(f32x4*)(smem + swz(srow, (KB) + 1536)) = a6;                             \
  *(f32x4*)(smem + swz(srow, (KB) + 1792)) = a7;                             \
} while (0)

__global__ __launch_bounds__(512, 2)
void rnn_fused(const float* __restrict__ x, const float* __restrict__ Whx,
               const float* __restrict__ Whh, const float* __restrict__ Wph,
               const float* __restrict__ Bh, const float* __restrict__ Bp,
               float* __restrict__ out,
               u64* __restrict__ h0buf, u64* __restrict__ h1buf,
               unsigned* __restrict__ flags) {
  extern __shared__ char smem[];
  const int tid = (int)threadIdx.x;
  const int lane = tid & 63;
  const int wv = tid >> 6;       // 0..7
  const int ci = wv & 3;         // 16-col group within WG
  const int kh = wv >> 2;        // K-half (0/1)

  // ---- ID phase: XCD self-identification with overflow detector + fallback
  // ctl[0..7]=per-XCD tickets, ctl[8]=arrive, ctl[9]=broken, ctl[10]=fallback
  unsigned* ctl = flags + 256;
  __shared__ unsigned s_ids[3];
  if (tid == 0) {
    unsigned xcc;
    asm volatile("s_getreg_b32 %0, hwreg(HW_REG_XCC_ID)" : "=s"(xcc));
    xcc &= 7u;
    unsigned tk = atomicAdd(&ctl[xcc], 1u);
    if (tk >= 32u) st_flag(&ctl[9], 1u);     // placement/xcc broken
    asm volatile("s_waitcnt vmcnt(0)" ::: "memory");  // broken visible first
    atomicAdd(&ctl[8], 1u);                  // arrive
    while (ld_flag(&ctl[8]) < 256u) __builtin_amdgcn_s_sleep(2);
    unsigned rg_, cg_, md_;
    if (ld_flag(&ctl[9]) != 0u) {            // fallback: LLC protocol (== R7)
      unsigned o = atomicAdd(&ctl[10], 1u);
      rg_ = o >> 5; cg_ = o & 31u; md_ = 0u;
    } else {                                 // clean: rowgroup == this XCD
      rg_ = xcc; cg_ = tk; md_ = 1u;
    }
    s_ids[0] = rg_; s_ids[1] = cg_; s_ids[2] = md_;
  }
  __syncthreads();
  const int rg = (int)s_ids[0];  // rowgroup 0..7 (32 rows, barrier domain)
  const int cg = (int)s_ids[1];  // colgroup 0..31 (64 hidden cols)
  const bool l2m = s_ids[2] != 0u;
  const int r0 = rg * 32;
  const int n0 = cg * 64;

  const int brow = lane & 15;    // batch row within 16-row tile; also A-row
  const int nq = lane >> 4;      // k-segment / D col-quad
  const int klo = nq * 8;
  const int wcol = n0 + ci * 16 + brow;   // this lane's hidden col (A operand)

  // ---- persistent A fragments in VGPRs (one-time gather, cached path)
  short8 wa[32];  // Whh^T: 16 cols x 1024 k (this wave's K-half)
#pragma unroll
  for (int kt = 0; kt < 32; ++kt) {
    const float* wp = Whh + (size_t)(kh * 1024 + kt * 32 + klo) * kH + wcol;
#pragma unroll
    for (int jj = 0; jj < 8; ++jj) wa[kt][jj] = (short)f2bf(wp[(size_t)jj * kH]);
  }
  short8 wx[4];   // Whx^T: 16 cols x 128 k (K-half of 256)
#pragma unroll
  for (int kt = 0; kt < 4; ++kt) {
    const float* wp = Whx + (size_t)(kh * 128 + kt * 32 + klo) * kH + wcol;
#pragma unroll
    for (int jj = 0; jj < 8; ++jj) wx[kt][jj] = (short)f2bf(wp[(size_t)jj * kH]);
  }

  const f32x4 bh = *(const f32x4*)(Bh + n0 + ci * 16 + nq * 4);

  // stage geometry: thread -> (row, 16B chunk)
  const int srow = tid >> 4;     // 0..31
  const int sc16 = tid & 15;

  unsigned* gflags = flags + (rg << 5);  // 32 flags per rowgroup
  const float* pxA = x + (size_t)(r0 + brow) * (kS * kI);
  const float* pxB = x + (size_t)(r0 + 16 + brow) * (kS * kI);

  for (int t = 0; t < kS; ++t) {
    const u64* hc = (t & 1) ? h1buf : h0buf;
    u64* hn       = (t & 1) ? h0buf : h1buf;
    f32x4 acc0 = {0.f, 0.f, 0.f, 0.f};
    f32x4 acc1 = {0.f, 0.f, 0.f, 0.f};

    // ---- x_t @ Whx over this wave's K-half (no h dep: overlaps flag wait)
#pragma unroll
    for (int kt = 0; kt < 4; ++kt) {
      const int k = kh * 128 + kt * 32 + klo;
      f32x4 xa = *(const f32x4*)(pxA + (size_t)t * kI + k);
      f32x4 xb = *(const f32x4*)(pxA + (size_t)t * kI + k + 4);
      f32x4 ya = *(const f32x4*)(pxB + (size_t)t * kI + k);
      f32x4 yb = *(const f32x4*)(pxB + (size_t)t * kI + k + 4);
      short8 b0, b1;
#pragma unroll
      for (int jj = 0; jj < 4; ++jj) {
        b0[jj] = (short)f2bf(xa[jj]); b0[jj + 4] = (short)f2bf(xb[jj]);
        b1[jj] = (short)f2bf(ya[jj]); b1[jj + 4] = (short)f2bf(yb[jj]);
      }
      acc0 = MFMA16(wx[kt], b0, acc0);
      acc1 = MFMA16(wx[kt], b1, acc1);
    }

    // ---- wait for h_t: only wave 0 polls, rest park at barrier
    if (t > 0 && wv == 0) {
      if (l2m) {
        while (!__all((int)(ld_flag_l2(&gflags[lane & 31]) >= (unsigned)t)))
          __builtin_amdgcn_s_sleep(1);
      } else {
        while (!__all((int)(ld_flag(&gflags[lane & 31]) >= (unsigned)t)))
          __builtin_amdgcn_s_sleep(2);
      }
      asm volatile("" ::: "memory");
    }
    __syncthreads();

    // ---- cooperative stage: h[32 x 2048] -> LDS, 16B loads, 8 in flight
    {
      const char* hp = (const char*)hc + (size_t)(r0 + srow) * 4096 + sc16 * 16;
      if (l2m) {
        STAGE_BATCH(hp, sc16 * 16, " sc0");              // XCD-local L2 hits
        STAGE_BATCH(hp + 2048, sc16 * 16 + 2048, " sc0");
      } else {
        STAGE_BATCH(hp, sc16 * 16, " sc0 sc1");          // LLC path (R7)
        STAGE_BATCH(hp + 2048, sc16 * 16 + 2048, " sc0 sc1");
      }
    }
    __syncthreads();

    // ---- h_t @ Whh: A from VGPR, B from swizzled LDS
#pragma unroll
    for (int kt = 0; kt < 32; ++kt) {
      const int kb = (kh * 1024 + kt * 32 + klo) * 2;
      short8 hb0 = *(const short8*)(smem + swz(brow, kb));
      short8 hb1 = *(const short8*)(smem + swz(brow + 16, kb));
      acc0 = MFMA16(wa[kt], hb0, acc0);
      acc1 = MFMA16(wa[kt], hb1, acc1);
    }

    // ---- K-half handoff (non-atomic zone; one owner per slot)
    if (kh == 1) {
      *zslot(smem, brow, ci * 4 + nq) = acc0;
      *zslot(smem, brow + 16, ci * 4 + nq) = acc1;
    }
    __syncthreads();

    // ---- kh==0: combine halves, tanh, pack 4 bf16 -> one 8B store per tile
    if (kh == 0) {
      f32x4 s0 = *zslot(smem, brow, ci * 4 + nq);
      f32x4 s1 = *zslot(smem, brow + 16, ci * 4 + nq);
      u64 v0 = 0, v1 = 0;
#pragma unroll
      for (int jj = 0; jj < 4; ++jj) {
        v0 |= (u64)f2bf(fast_tanh(acc0[jj] + s0[jj] + bh[jj])) << (16 * jj);
        v1 |= (u64)f2bf(fast_tanh(acc1[jj] + s1[jj] + bh[jj])) << (16 * jj);
      }
      const int qoff = (n0 >> 2) + ci * 4 + nq;
      u64* p0 = hn + (size_t)(r0 + brow) * 512 + qoff;
      u64* p1 = hn + (size_t)(r0 + 16 + brow) * 512 + qoff;
      if (l2m) { *p0 = v0; *p1 = v1; }       // write-through to XCD L2
      else     { st_h8(p0, v0); st_h8(p1, v1); }
    }

    // ---- release: __syncthreads drains vmcnt (stores ack'd), then flag
    __syncthreads();
    if (tid == 0) {
      if (l2m) st_flag_l2(&gflags[cg], (unsigned)(t + 1));
      else     st_flag(&gflags[cg], (unsigned)(t + 1));
    }
  }

  // ================= epilogue: out = h_final @ Wph + Bp =================
  if (wv == 0) {
    if (l2m) {
      while (!__all((int)(ld_flag_l2(&gflags[lane & 31]) >= (unsigned)kS)))
        __builtin_amdgcn_s_sleep(1);
    } else {
      while (!__all((int)(ld_flag(&gflags[lane & 31]) >= (unsigned)kS)))
        __builtin_amdgcn_s_sleep(2);
    }
    asm volatile("" ::: "memory");
  }
  __syncthreads();

  // stage Wph^T slice [32 cls-cols][2048 k] into h-stage region
  {
    const int c = tid & 31;
    const int kk = tid >> 5;  // 16 k-stripes
    for (int k = kk; k < kH; k += 16)
      *(unsigned short*)(smem + swz(c, k * 2)) = f2bf(Wph[(size_t)k * kC + cg * 32 + c]);
  }
  __syncthreads();

  // waves 0..3 active: (ci2 = wv&1 -> 16 cls-cols, kh2 = wv>>1 -> K-half)
  const bool act = (wv < 4);
  const int ci2 = wv & 1;
  const int kh2 = (wv >> 1) & 1;
  f32x4 oacc0 = {0.f, 0.f, 0.f, 0.f};
  f32x4 oacc1 = {0.f, 0.f, 0.f, 0.f};
  if (act) {
    const u64* phA = h0buf + (size_t)(r0 + brow) * 512;   // h_final (t=511)
    const u64* phB = h0buf + (size_t)(r0 + 16 + brow) * 512;
#pragma unroll 8
    for (int kt = 0; kt < 32; ++kt) {
      const int gk = kh2 * 1024 + kt * 32 + klo;
      short8 a = *(const short8*)(smem + swz(ci2 * 16 + brow, gk * 2));
      union { u64 q[2]; short8 s; } uA, uB;
      if (l2m) {
        uA.q[0] = ld8_l2(phA + (gk >> 2)); uA.q[1] = ld8_l2(phA + (gk >> 2) + 1);
        uB.q[0] = ld8_l2(phB + (gk >> 2)); uB.q[1] = ld8_l2(phB + (gk >> 2) + 1);
      } else {
        uA.q[0] = ld_h8(phA + (gk >> 2)); uA.q[1] = ld_h8(phA + (gk >> 2) + 1);
        uB.q[0] = ld_h8(phB + (gk >> 2)); uB.q[1] = ld_h8(phB + (gk >> 2) + 1);
      }
      oacc0 = MFMA16(a, uA.s, oacc0);
      oacc1 = MFMA16(a, uB.s, oacc1);
    }
  }
  if (act && kh2 == 1) {
    *zslot2(smem, brow, ci2 * 4 + nq) = oacc0;
    *zslot2(smem, brow + 16, ci2 * 4 + nq) = oacc1;
  }
  __syncthreads();
  if (act && kh2 == 0) {
    f32x4 s0 = *zslot2(smem, brow, ci2 * 4 + nq);
    f32x4 s1 = *zslot2(smem, brow + 16, ci2 * 4 + nq);
    const int ocol = cg * 32 + ci2 * 16 + nq * 4;
    const f32x4 bp = *(const f32x4*)(Bp + ocol);
#pragma unroll
    for (int jj = 0; jj < 4; ++jj) {
      out[(size_t)(r0 + brow) * kC + ocol + jj] = oacc0[jj] + s0[jj] + bp[jj];
      out[(size_t)(r0 + 16 + brow) * kC + ocol + jj] = oacc1[jj] + s1[jj] + bp[jj];
    }
  }
}

extern "C" void kernel_launch(void* const* d_in, const int* in_sizes, int n_in,
                              void* d_out, int out_size, void* d_ws, size_t ws_size,
                              hipStream_t stream) {
  const float* x   = (const float*)d_in[0];
  const float* Whx = (const float*)d_in[1];
  const float* Whh = (const float*)d_in[2];
  const float* Wph = (const float*)d_in[3];
  const float* Bh  = (const float*)d_in[4];
  const float* Bp  = (const float*)d_in[5];
  float* out = (float*)d_out;

  char* ws = (char*)d_ws;
  u64* h0         = (u64*)(ws);                   // 1 MB: h ping
  u64* h1         = (u64*)(ws + (1 << 20));       // 1 MB: h pong
  unsigned* flags = (unsigned*)(ws + (2 << 20));  // flags[256] + ctl[...]

  hipMemsetAsync(h0, 0, (size_t)kBt * kH * sizeof(unsigned short), stream);  // h_0 = 0
  hipMemsetAsync(flags, 0, 4096, stream);  // flags + tickets/arrive/broken/g2

  dim3 grid(256), block(512);
  size_t lds = 139264;  // 128K h-stage + 8K zone  => exactly 1 WG/CU
  hipLaunchKernelGGL(rnn_fused, grid, block, lds, stream,
                     x, Whx, Whh, Wph, Bh, Bp, out, h0, h1, flags);
}

// Round 9
// 5278.299 us; speedup vs baseline: 1300.6046x; 1300.6046x over previous
//
#include <hip/hip_runtime.h>
#include <hip/hip_bf16.h>

typedef __attribute__((ext_vector_type(8))) short short8;
typedef __attribute__((ext_vector_type(4))) float f32x4;
typedef unsigned long long u64;

#define MFMA16(A, B, C) __builtin_amdgcn_mfma_f32_16x16x32_bf16((A), (B), (C), 0, 0, 0)

static constexpr int kS = 512;   // seq
static constexpr int kI = 256;   // in_dim
static constexpr int kH = 2048;  // hidden
static constexpr int kC = 1024;  // classes
static constexpr int kBt = 256;  // batch

// WG tile: 32 batch rows x 64 hidden cols. Grid 256 = 8 rowgroups x 32 colgroups.
// Whh/Whx in VGPRs (wave: 16 cols x K-half). Steady-state loop has ZERO
// __syncthreads: K-half groups (waves 0-3 / 4-7) each stage ONLY the K-byte
// range they consume, sync via monotonic LDS counters; zone is parity
// double-buffered. Cross-WG sync: LLC agent-scope atomics only (R2-R7).
// LDS map (dynamic, 147456 B):
//   [0,      131072): h-stage [32 rows][2048 k] bf16, stride 4096 B, XOR swizzle
//                     (epilogue reuse: Wph^T [32 cls-cols][2048 k])
//   [131072, 139264): zone parity 0: [32 rows][16 quads f32x4], XOR swizzle
//   [139264, 147456): zone parity 1
static constexpr int ZONE_OFF = 131072;

__device__ __forceinline__ int swz(int row, int kbyte) {
  return row * 4096 + (kbyte ^ ((row & 7) << 4));
}
__device__ __forceinline__ f32x4* zslotp(char* smem, int p, int row, int quad) {
  return (f32x4*)(smem + ZONE_OFF + p * 8192 + row * 256 + (((quad ^ row) & 15) << 4));
}
__device__ __forceinline__ f32x4* zslot2(char* smem, int row, int quad) {  // epilogue
  return (f32x4*)(smem + ZONE_OFF + row * 128 + (((quad ^ row) & 7) << 4));
}

__device__ __forceinline__ unsigned short f2bf(float f) {  // RNE fp32->bf16
  unsigned u = __float_as_uint(f);
  u += 0x7fffu + ((u >> 16) & 1u);
  return (unsigned short)(u >> 16);
}

__device__ __forceinline__ float fast_tanh(float v) {
  float a = __builtin_fabsf(v);
  float e = __expf(-2.0f * a);
  float r = (1.0f - e) / (1.0f + e);
  return __builtin_copysignf(r, v);
}

// Validated LLC-coherent intrinsic path (rounds 2-5, 7).
__device__ __forceinline__ u64 ld_h8(const u64* p) {
  return __hip_atomic_load(p, __ATOMIC_RELAXED, __HIP_MEMORY_SCOPE_AGENT);
}
__device__ __forceinline__ void st_h8(u64* p, u64 v) {
  __hip_atomic_store(p, v, __ATOMIC_RELAXED, __HIP_MEMORY_SCOPE_AGENT);
}
__device__ __forceinline__ unsigned ld_flag(const unsigned* p) {
  return __hip_atomic_load(p, __ATOMIC_RELAXED, __HIP_MEMORY_SCOPE_AGENT);
}
__device__ __forceinline__ void st_flag(unsigned* p, unsigned v) {
  __hip_atomic_store(p, v, __ATOMIC_RELAXED, __HIP_MEMORY_SCOPE_AGENT);
}
// LDS counter helpers (monotonic; no resets -> no reuse races).
__device__ __forceinline__ unsigned ld_cnt(unsigned* c) {
  return __hip_atomic_load(c, __ATOMIC_RELAXED, __HIP_MEMORY_SCOPE_WORKGROUP);
}

__global__ __launch_bounds__(512, 2)
void rnn_fused(const float* __restrict__ x, const float* __restrict__ Whx,
               const float* __restrict__ Whh, const float* __restrict__ Wph,
               const float* __restrict__ Bh, const float* __restrict__ Bp,
               float* __restrict__ out,
               u64* __restrict__ h0buf, u64* __restrict__ h1buf,
               unsigned* __restrict__ flags) {
  extern __shared__ char smem[];
  // cnts[0]=stage kh0, cnts[1]=stage kh1, cnts[2]=zone ready, cnts[3]=h stored
  __shared__ unsigned cnts[4];
  const int tid = (int)threadIdx.x;
  const int lane = tid & 63;
  const int wv = tid >> 6;       // 0..7
  const int ci = wv & 3;         // 16-col group within WG
  const int kh = wv >> 2;        // K-half (0/1)
  const int wg = (int)blockIdx.x;
  const int rg = wg >> 5;        // 0..7  : rowgroup (32 rows, barrier domain)
  const int cg = wg & 31;        // 0..31 : colgroup (64 hidden cols)
  const int r0 = rg * 32;
  const int n0 = cg * 64;

  if (tid < 4) cnts[tid] = 0u;

  const int brow = lane & 15;    // batch row within 16-row tile; also A-row
  const int nq = lane >> 4;      // k-segment / D col-quad
  const int klo = nq * 8;
  const int wcol = n0 + ci * 16 + brow;   // this lane's hidden col (A operand)

  // ---- persistent A fragments in VGPRs (one-time gather, cached path)
  short8 wa[32];  // Whh^T: 16 cols x 1024 k (this wave's K-half)
#pragma unroll
  for (int kt = 0; kt < 32; ++kt) {
    const float* wp = Whh + (size_t)(kh * 1024 + kt * 32 + klo) * kH + wcol;
#pragma unroll
    for (int jj = 0; jj < 8; ++jj) wa[kt][jj] = (short)f2bf(wp[(size_t)jj * kH]);
  }
  short8 wx[4];   // Whx^T: 16 cols x 128 k (K-half of 256)
#pragma unroll
  for (int kt = 0; kt < 4; ++kt) {
    const float* wp = Whx + (size_t)(kh * 128 + kt * 32 + klo) * kH + wcol;
#pragma unroll
    for (int jj = 0; jj < 8; ++jj) wx[kt][jj] = (short)f2bf(wp[(size_t)jj * kH]);
  }

  const f32x4 bh = *(const f32x4*)(Bh + n0 + ci * 16 + nq * 4);

  // stage geometry: each K-half GROUP (256 threads) stages its own byte range
  // [2048*kh, 2048*kh+2048) for all 32 rows; thread -> (row, 8 x 16B columns)
  const int gtid = tid & 255;
  const int srow = gtid >> 3;            // 0..31
  const int kb0 = kh * 2048 + (gtid & 7) * 16;  // first chunk byte in row

  unsigned* gflags = flags + (rg << 5);  // 32 flags per rowgroup
  const float* pxA = x + (size_t)(r0 + brow) * (kS * kI);
  const float* pxB = x + (size_t)(r0 + 16 + brow) * (kS * kI);

  __syncthreads();  // cnts zeroed; LDS clean

  for (int t = 0; t < kS; ++t) {
    const u64* hc = (t & 1) ? h1buf : h0buf;
    u64* hn       = (t & 1) ? h0buf : h1buf;
    const int p   = t & 1;
    f32x4 acc0 = {0.f, 0.f, 0.f, 0.f};
    f32x4 acc1 = {0.f, 0.f, 0.f, 0.f};

    // ---- x_t @ Whx over this wave's K-half (no h dep: overlaps flag wait)
#pragma unroll
    for (int kt = 0; kt < 4; ++kt) {
      const int k = kh * 128 + kt * 32 + klo;
      f32x4 xa = *(const f32x4*)(pxA + (size_t)t * kI + k);
      f32x4 xb = *(const f32x4*)(pxA + (size_t)t * kI + k + 4);
      f32x4 ya = *(const f32x4*)(pxB + (size_t)t * kI + k);
      f32x4 yb = *(const f32x4*)(pxB + (size_t)t * kI + k + 4);
      short8 b0, b1;
#pragma unroll
      for (int jj = 0; jj < 4; ++jj) {
        b0[jj] = (short)f2bf(xa[jj]); b0[jj + 4] = (short)f2bf(xb[jj]);
        b1[jj] = (short)f2bf(ya[jj]); b1[jj + 4] = (short)f2bf(yb[jj]);
      }
      acc0 = MFMA16(wx[kt], b0, acc0);
      acc1 = MFMA16(wx[kt], b1, acc1);
    }

    // ---- every wave waits for h_t itself (validated LLC flag poll)
    if (t > 0) {
      while (!__all((int)(ld_flag(&gflags[lane & 31]) >= (unsigned)t)))
        __builtin_amdgcn_s_sleep(2);
      asm volatile("" ::: "memory");
    }

    // ---- stage my group's K-half: 16 x 16B loads, counted vmcnt split
    {
      const char* hp = (const char*)hc + (size_t)(r0 + srow) * 4096 + kb0;
      f32x4 a0, a1, a2, a3, a4, a5, a6, a7, b0, b1, b2, b3, b4, b5, b6, b7;
      asm volatile(
          "global_load_dwordx4 %0, %16, off sc0 sc1\n\t"
          "global_load_dwordx4 %1, %16, off offset:128 sc0 sc1\n\t"
          "global_load_dwordx4 %2, %16, off offset:256 sc0 sc1\n\t"
          "global_load_dwordx4 %3, %16, off offset:384 sc0 sc1\n\t"
          "global_load_dwordx4 %4, %16, off offset:512 sc0 sc1\n\t"
          "global_load_dwordx4 %5, %16, off offset:640 sc0 sc1\n\t"
          "global_load_dwordx4 %6, %16, off offset:768 sc0 sc1\n\t"
          "global_load_dwordx4 %7, %16, off offset:896 sc0 sc1\n\t"
          "global_load_dwordx4 %8, %16, off offset:1024 sc0 sc1\n\t"
          "global_load_dwordx4 %9, %16, off offset:1152 sc0 sc1\n\t"
          "global_load_dwordx4 %10, %16, off offset:1280 sc0 sc1\n\t"
          "global_load_dwordx4 %11, %16, off offset:1408 sc0 sc1\n\t"
          "global_load_dwordx4 %12, %16, off offset:1536 sc0 sc1\n\t"
          "global_load_dwordx4 %13, %16, off offset:1664 sc0 sc1\n\t"
          "global_load_dwordx4 %14, %16, off offset:1792 sc0 sc1\n\t"
          "global_load_dwordx4 %15, %16, off offset:1920 sc0 sc1"
          : "=&v"(a0), "=&v"(a1), "=&v"(a2), "=&v"(a3),
            "=&v"(a4), "=&v"(a5), "=&v"(a6), "=&v"(a7),
            "=&v"(b0), "=&v"(b1), "=&v"(b2), "=&v"(b3),
            "=&v"(b4), "=&v"(b5), "=&v"(b6), "=&v"(b7)
          : "v"(hp) : "memory");
      asm volatile("s_waitcnt vmcnt(8)" ::: "memory");
      __builtin_amdgcn_sched_barrier(0);
      *(f32x4*)(smem + swz(srow, kb0))        = a0;
      *(f32x4*)(smem + swz(srow, kb0 + 128))  = a1;
      *(f32x4*)(smem + swz(srow, kb0 + 256))  = a2;
      *(f32x4*)(smem + swz(srow, kb0 + 384))  = a3;
      *(f32x4*)(smem + swz(srow, kb0 + 512))  = a4;
      *(f32x4*)(smem + swz(srow, kb0 + 640))  = a5;
      *(f32x4*)(smem + swz(srow, kb0 + 768))  = a6;
      *(f32x4*)(smem + swz(srow, kb0 + 896))  = a7;
      asm volatile("s_waitcnt vmcnt(0)" ::: "memory");
      __builtin_amdgcn_sched_barrier(0);
      *(f32x4*)(smem + swz(srow, kb0 + 1024)) = b0;
      *(f32x4*)(smem + swz(srow, kb0 + 1152)) = b1;
      *(f32x4*)(smem + swz(srow, kb0 + 1280)) = b2;
      *(f32x4*)(smem + swz(srow, kb0 + 1408)) = b3;
      *(f32x4*)(smem + swz(srow, kb0 + 1536)) = b4;
      *(f32x4*)(smem + swz(srow, kb0 + 1664)) = b5;
      *(f32x4*)(smem + swz(srow, kb0 + 1792)) = b6;
      *(f32x4*)(smem + swz(srow, kb0 + 1920)) = b7;
    }
    // ---- group mini-barrier (my 4 waves staged my K-half)
    {
      asm volatile("s_waitcnt lgkmcnt(0)" ::: "memory");
      if (lane == 0) atomicAdd(&cnts[kh], 1u);
      const unsigned tgt = 4u * (unsigned)(t + 1);
      while (ld_cnt(&cnts[kh]) < tgt) {}
      asm volatile("s_waitcnt lgkmcnt(0)" ::: "memory");
      __builtin_amdgcn_sched_barrier(0);
    }

    // ---- h_t @ Whh: A from VGPR, B from swizzled LDS (my K-half only)
#pragma unroll
    for (int kt = 0; kt < 32; ++kt) {
      const int kb = (kh * 1024 + kt * 32 + klo) * 2;
      short8 hb0 = *(const short8*)(smem + swz(brow, kb));
      short8 hb1 = *(const short8*)(smem + swz(brow + 16, kb));
      acc0 = MFMA16(wa[kt], hb0, acc0);
      acc1 = MFMA16(wa[kt], hb1, acc1);
    }

    if (kh == 1) {
      // ---- publish partial sums to zone[parity], signal via LDS counter
      *zslotp(smem, p, brow, ci * 4 + nq) = acc0;
      *zslotp(smem, p, brow + 16, ci * 4 + nq) = acc1;
      asm volatile("s_waitcnt lgkmcnt(0)" ::: "memory");
      if (lane == 0) atomicAdd(&cnts[2], 1u);
    } else {
      // ---- wait zone, combine, tanh, pack, store h via LLC, signal stored
      const unsigned tgt = 4u * (unsigned)(t + 1);
      while (ld_cnt(&cnts[2]) < tgt) {}
      asm volatile("s_waitcnt lgkmcnt(0)" ::: "memory");
      __builtin_amdgcn_sched_barrier(0);
      f32x4 s0 = *zslotp(smem, p, brow, ci * 4 + nq);
      f32x4 s1 = *zslotp(smem, p, brow + 16, ci * 4 + nq);
      u64 v0 = 0, v1 = 0;
#pragma unroll
      for (int jj = 0; jj < 4; ++jj) {
        v0 |= (u64)f2bf(fast_tanh(acc0[jj] + s0[jj] + bh[jj])) << (16 * jj);
        v1 |= (u64)f2bf(fast_tanh(acc1[jj] + s1[jj] + bh[jj])) << (16 * jj);
      }
      const int qoff = (n0 >> 2) + ci * 4 + nq;
      st_h8(hn + (size_t)(r0 + brow) * 512 + qoff, v0);
      st_h8(hn + (size_t)(r0 + 16 + brow) * 512 + qoff, v1);
      asm volatile("s_waitcnt vmcnt(0)" ::: "memory");  // stores ack'd at LLC
      if (lane == 0) atomicAdd(&cnts[3], 1u);
      if (tid == 0) {  // all 4 kh0 waves drained -> release rowgroup flag
        while (ld_cnt(&cnts[3]) < tgt) {}
        st_flag(&gflags[cg], (unsigned)(t + 1));
      }
    }
  }

  // ================= epilogue: out = h_final @ Wph + Bp =================
  while (!__all((int)(ld_flag(&gflags[lane & 31]) >= (unsigned)kS)))
    __builtin_amdgcn_s_sleep(2);
  asm volatile("" ::: "memory");
  __syncthreads();

  // stage Wph^T slice [32 cls-cols][2048 k] into h-stage region
  {
    const int c = tid & 31;
    const int kk = tid >> 5;  // 16 k-stripes
    for (int k = kk; k < kH; k += 16)
      *(unsigned short*)(smem + swz(c, k * 2)) = f2bf(Wph[(size_t)k * kC + cg * 32 + c]);
  }
  __syncthreads();

  // waves 0..3 active: (ci2 = wv&1 -> 16 cls-cols, kh2 = wv>>1 -> K-half)
  const bool act = (wv < 4);
  const int ci2 = wv & 1;
  const int kh2 = (wv >> 1) & 1;
  f32x4 oacc0 = {0.f, 0.f, 0.f, 0.f};
  f32x4 oacc1 = {0.f, 0.f, 0.f, 0.f};
  if (act) {
    const u64* phA = h0buf + (size_t)(r0 + brow) * 512;   // h_final (t=511 -> h0)
    const u64* phB = h0buf + (size_t)(r0 + 16 + brow) * 512;
#pragma unroll 8
    for (int kt = 0; kt < 32; ++kt) {
      const int gk = kh2 * 1024 + kt * 32 + klo;
      short8 a = *(const short8*)(smem + swz(ci2 * 16 + brow, gk * 2));
      union { u64 q[2]; short8 s; } uA, uB;
      uA.q[0] = ld_h8(phA + (gk >> 2)); uA.q[1] = ld_h8(phA + (gk >> 2) + 1);
      uB.q[0] = ld_h8(phB + (gk >> 2)); uB.q[1] = ld_h8(phB + (gk >> 2) + 1);
      oacc0 = MFMA16(a, uA.s, oacc0);
      oacc1 = MFMA16(a, uB.s, oacc1);
    }
  }
  if (act && kh2 == 1) {
    *zslot2(smem, brow, ci2 * 4 + nq) = oacc0;
    *zslot2(smem, brow + 16, ci2 * 4 + nq) = oacc1;
  }
  __syncthreads();
  if (act && kh2 == 0) {
    f32x4 s0 = *zslot2(smem, brow, ci2 * 4 + nq);
    f32x4 s1 = *zslot2(smem, brow + 16, ci2 * 4 + nq);
    const int ocol = cg * 32 + ci2 * 16 + nq * 4;
    const f32x4 bp = *(const f32x4*)(Bp + ocol);
#pragma unroll
    for (int jj = 0; jj < 4; ++jj) {
      out[(size_t)(r0 + brow) * kC + ocol + jj] = oacc0[jj] + s0[jj] + bp[jj];
      out[(size_t)(r0 + 16 + brow) * kC + ocol + jj] = oacc1[jj] + s1[jj] + bp[jj];
    }
  }
}

extern "C" void kernel_launch(void* const* d_in, const int* in_sizes, int n_in,
                              void* d_out, int out_size, void* d_ws, size_t ws_size,
                              hipStream_t stream) {
  const float* x   = (const float*)d_in[0];
  const float* Whx = (const float*)d_in[1];
  const float* Whh = (const float*)d_in[2];
  const float* Wph = (const float*)d_in[3];
  const float* Bh  = (const float*)d_in[4];
  const float* Bp  = (const float*)d_in[5];
  float* out = (float*)d_out;

  char* ws = (char*)d_ws;
  u64* h0         = (u64*)(ws);                   // 1 MB: h ping
  u64* h1         = (u64*)(ws + (1 << 20));       // 1 MB: h pong
  unsigned* flags = (unsigned*)(ws + (2 << 20));  // 8 groups x 32 step flags

  hipMemsetAsync(h0, 0, (size_t)kBt * kH * sizeof(unsigned short), stream);  // h_0 = 0
  hipMemsetAsync(flags, 0, 4096, stream);                                    // reset barrier

  dim3 grid(256), block(512);
  size_t lds = 147456;  // 128K h-stage + 2 x 8K zone
  hipLaunchKernelGGL(rnn_fused, grid, block, lds, stream,
                     x, Whx, Whh, Wph, Bh, Bp, out, h0, h1, flags);
}